// Round 8
// baseline (102.496 us; speedup 1.0000x reference)
//
#include <hip/hip_runtime.h>
#include <hip/hip_bf16.h>

#define TGT   64
#define SRCN  64
#define BATCH 32
#define HID   512
#define ATT   512
#define MROWS (TGT * BATCH)          // 2048 rows per z

typedef __bf16 bf16_t;
typedef __bf16 bf16x8 __attribute__((ext_vector_type(8)));
typedef float  f32x4  __attribute__((ext_vector_type(4)));

// HW transcendentals (round-3 lesson: libm exp2f/__frcp_rn cost 29 us).
__device__ __forceinline__ float fast_exp2(float x) {
#if __has_builtin(__builtin_amdgcn_exp2f)
  return __builtin_amdgcn_exp2f(x);
#else
  float r; asm("v_exp_f32 %0, %1\n\ts_nop 1" : "=v"(r) : "v"(x)); return r;
#endif
}
__device__ __forceinline__ float fast_rcp(float x) {
#if __has_builtin(__builtin_amdgcn_rcpf)
  return __builtin_amdgcn_rcpf(x);
#else
  float r; asm("v_rcp_f32 %0, %1\n\ts_nop 1" : "=v"(r) : "v"(x)); return r;
#endif
}

#define MFMA(a, b, c) __builtin_amdgcn_mfma_f32_16x16x32_bf16((a), (b), (c), 0, 0, 0)

// ---------------------------------------------------------------------------
// proj_gemm v2.1: same as R5-R7 except ALL global loads for an iteration
// (A: 4x float4, B: 16x dword) are issued before any LDS write, doubling
// per-wave VMEM in flight (compiler uses partial vmcnt for the A-writes).
// ---------------------------------------------------------------------------
__global__ __launch_bounds__(256) void proj_gemm(
    const float* __restrict__ h_t, const float* __restrict__ srcp,
    const float* __restrict__ Wa, float* __restrict__ C)
{
  const int z = blockIdx.z;
  const float* __restrict__ A = z ? srcp : h_t;
  const int mbase = blockIdx.x * 64;
  const int nbase = blockIdx.y * 64;

  __shared__ bf16_t Ah[64][72];
  __shared__ bf16_t Al[64][72];
  __shared__ bf16_t Bh[64][72];   // transposed: Bh[n][k]
  __shared__ bf16_t Bl[64][72];

  const int tid  = threadIdx.x;
  const int lane = tid & 63;
  const int wv   = tid >> 6;          // 0..3
  const int wm   = (wv & 1) * 32;
  const int wn   = (wv >> 1) * 32;
  const int l15  = lane & 15;
  const int qd   = lane >> 4;

  const int arow = tid >> 2;
  const int akc  = (tid & 3) * 16;
  const int bn = tid & 63;
  const int bkg = (tid >> 6) * 16;

  const float* Aptr = A + (size_t)(mbase + arow) * HID + akc;
  const float* Bptr = Wa + (size_t)(z * HID + bkg) * ATT + nbase + bn;

  f32x4 acc00 = {0.f, 0.f, 0.f, 0.f};
  f32x4 acc01 = acc00, acc10 = acc00, acc11 = acc00;

  for (int kb = 0; kb < HID; kb += 64) {
    if (kb) __syncthreads();

    // ---- issue ALL global loads first (A 64B + B 64B per lane in flight) ----
    float4 a0 = *(const float4*)(Aptr + kb);
    float4 a1 = *(const float4*)(Aptr + kb + 4);
    float4 a2 = *(const float4*)(Aptr + kb + 8);
    float4 a3 = *(const float4*)(Aptr + kb + 12);
    const float* bp = Bptr + (size_t)kb * ATT;
    float bv[16];
#pragma unroll
    for (int j = 0; j < 16; ++j) bv[j] = bp[(size_t)j * ATT];

    // ---- convert + stage A ----
    {
      float av[16] = {a0.x, a0.y, a0.z, a0.w, a1.x, a1.y, a1.z, a1.w,
                      a2.x, a2.y, a2.z, a2.w, a3.x, a3.y, a3.z, a3.w};
      bf16x8 hi0, hi1, lo0, lo1;
#pragma unroll
      for (int j = 0; j < 8; ++j) {
        bf16_t h = (bf16_t)av[j];
        hi0[j] = h;
        lo0[j] = (bf16_t)(av[j] - (float)h);
        bf16_t h2 = (bf16_t)av[j + 8];
        hi1[j] = h2;
        lo1[j] = (bf16_t)(av[j + 8] - (float)h2);
      }
      *(bf16x8*)&Ah[arow][akc]     = hi0;
      *(bf16x8*)&Ah[arow][akc + 8] = hi1;
      *(bf16x8*)&Al[arow][akc]     = lo0;
      *(bf16x8*)&Al[arow][akc + 8] = lo1;
    }

    // ---- convert + stage B transposed ----
    {
      bf16x8 hi0, hi1, lo0, lo1;
#pragma unroll
      for (int j = 0; j < 8; ++j) {
        bf16_t h = (bf16_t)bv[j];
        hi0[j] = h;
        lo0[j] = (bf16_t)(bv[j] - (float)h);
        bf16_t h2 = (bf16_t)bv[j + 8];
        hi1[j] = h2;
        lo1[j] = (bf16_t)(bv[j + 8] - (float)h2);
      }
      *(bf16x8*)&Bh[bn][bkg]     = hi0;
      *(bf16x8*)&Bh[bn][bkg + 8] = hi1;
      *(bf16x8*)&Bl[bn][bkg]     = lo0;
      *(bf16x8*)&Bl[bn][bkg + 8] = lo1;
    }
    __syncthreads();

#pragma unroll
    for (int h = 0; h < 2; ++h) {
      const int kh = h * 32 + qd * 8;
      bf16x8 ah0 = *(const bf16x8*)&Ah[wm + l15][kh];
      bf16x8 ah1 = *(const bf16x8*)&Ah[wm + 16 + l15][kh];
      bf16x8 al0 = *(const bf16x8*)&Al[wm + l15][kh];
      bf16x8 al1 = *(const bf16x8*)&Al[wm + 16 + l15][kh];
      bf16x8 bh0 = *(const bf16x8*)&Bh[wn + l15][kh];
      bf16x8 bh1 = *(const bf16x8*)&Bh[wn + 16 + l15][kh];
      bf16x8 bl0 = *(const bf16x8*)&Bl[wn + l15][kh];
      bf16x8 bl1 = *(const bf16x8*)&Bl[wn + 16 + l15][kh];

      acc00 = MFMA(ah0, bh0, acc00);
      acc01 = MFMA(ah0, bh1, acc01);
      acc10 = MFMA(ah1, bh0, acc10);
      acc11 = MFMA(ah1, bh1, acc11);
      acc00 = MFMA(al0, bh0, acc00);
      acc01 = MFMA(al0, bh1, acc01);
      acc10 = MFMA(al1, bh0, acc10);
      acc11 = MFMA(al1, bh1, acc11);
      acc00 = MFMA(ah0, bl0, acc00);
      acc01 = MFMA(ah0, bl1, acc01);
      acc10 = MFMA(ah1, bl0, acc10);
      acc11 = MFMA(ah1, bl1, acc11);
    }
  }

  float* Cz = C + (size_t)z * (MROWS * ATT);
#pragma unroll
  for (int r = 0; r < 4; ++r) {
    int row0 = mbase + wm + qd * 4 + r;
    int row1 = row0 + 16;
    int col0 = nbase + wn + l15;
    Cz[(size_t)row0 * ATT + col0]      = acc00[r];
    Cz[(size_t)row0 * ATT + col0 + 16] = acc01[r];
    Cz[(size_t)row1 * ATT + col0]      = acc10[r];
    Cz[(size_t)row1 * ATT + col0 + 16] = acc11[r];
  }
}

// ---------------------------------------------------------------------------
// attn_fused v5: HBM memory-level-parallelism fix.
// R4-R7 were stuck at ~29-31 us with only ~4x16B s_part loads in flight per
// wave (latency-bound on post-fill-cold HBM: R3 FETCH=34.9MB @ ~1.4 TB/s
// effective). v5: depth-4 rolling prefetch of s-rows (256B/lane in flight,
// ~4x MLP) + XCD swizzle (all 16 t-blocks of a batch b on one XCD -> s_part/
// src cached once per XCD, not 8x) + context unroll 16.
// Numerics unchanged from v4 (absmax 1.953e-3).
// ---------------------------------------------------------------------------
__global__ __launch_bounds__(512) void attn_fused(
    const float* __restrict__ ws, const float* __restrict__ srcp,
    const float* __restrict__ Va, float* __restrict__ out)
{
  const float* __restrict__ h_part = ws;
  const float* __restrict__ s_part = ws + (size_t)TGT * BATCH * ATT;
  const float SC = 2.8853900817779268f;   // 2*log2(e)

  // XCD swizzle: L%8 selects XCD (round-robin dispatch heuristic); give each
  // XCD 4 whole batches (all 16 t-blocks) -> per-XCD L2 reuse of s_part/src.
  const int L  = blockIdx.x;
  const int b  = (L & 7) + 8 * (L >> 7);
  const int t0 = ((L >> 3) & 15) * 4;

  const int tid  = threadIdx.x;
  const int lane = tid & 63;
  const int wv   = tid >> 6;              // 0..7

  __shared__ float scoreLds[4][64];
  __shared__ float attnLds[4][64];

  const int abase = lane * 8;

  // ---- issue the first 4 s-row loads immediately (depth-4 pipeline) ----
  const int s0 = wv * 8;
  const float* spB = s_part + ((size_t)s0 * BATCH + b) * ATT + abase;
  float4 P0[4], P1[4];
#pragma unroll
  for (int i = 0; i < 4; ++i) {
    P0[i] = *(const float4*)(spB + (size_t)i * BATCH * ATT);
    P1[i] = *(const float4*)(spB + (size_t)i * BATCH * ATT + 4);
  }

  // ---- h_part / Va loads + eH precompute overlap the s-load latency ----
  float va[8], eH[4][8];
  {
    float4 v0 = *(const float4*)(Va + abase);
    float4 v1 = *(const float4*)(Va + abase + 4);
    va[0] = v0.x; va[1] = v0.y; va[2] = v0.z; va[3] = v0.w;
    va[4] = v1.x; va[5] = v1.y; va[6] = v1.z; va[7] = v1.w;
  }
#pragma unroll
  for (int t = 0; t < 4; ++t) {
    const float* hp = h_part + ((size_t)(t0 + t) * BATCH + b) * ATT + abase;
    float4 h0 = *(const float4*)hp;
    float4 h1 = *(const float4*)(hp + 4);
    float hv[8] = {h0.x, h0.y, h0.z, h0.w, h1.x, h1.y, h1.z, h1.w};
#pragma unroll
    for (int j = 0; j < 8; ++j) eH[t][j] = fast_exp2(hv[j] * SC);
  }

  float vsum = 0.f;
#pragma unroll
  for (int j = 0; j < 8; ++j) vsum += va[j];
#pragma unroll
  for (int off = 32; off; off >>= 1) vsum += __shfl_xor(vsum, off);

  // ---- scores: 8 s-rows per wave, rolling depth-4 prefetch ----
#pragma unroll
  for (int i = 0; i < 8; ++i) {
    float4 c0 = P0[i & 3], c1 = P1[i & 3];
    if (i < 4) {
      P0[i & 3] = *(const float4*)(spB + (size_t)(i + 4) * BATCH * ATT);
      P1[i & 3] = *(const float4*)(spB + (size_t)(i + 4) * BATCH * ATT + 4);
    }
    float sv[8] = {c0.x, c0.y, c0.z, c0.w, c1.x, c1.y, c1.z, c1.w};
    float ex[8];
#pragma unroll
    for (int j = 0; j < 8; ++j) ex[j] = fast_exp2(sv[j] * SC);

    float q0 = 0.f, q1 = 0.f, q2 = 0.f, q3 = 0.f;
#pragma unroll
    for (int j = 0; j < 8; ++j) {
      float e = ex[j];
      float vj = va[j];
      float y0 = fmaf(e, eH[0][j], 1.0f);
      float y1 = fmaf(e, eH[1][j], 1.0f);
      float y2 = fmaf(e, eH[2][j], 1.0f);
      float y3 = fmaf(e, eH[3][j], 1.0f);
      float r01 = fast_rcp(y0 * y1);
      float r23 = fast_rcp(y2 * y3);
      q0 = fmaf(vj * y1, r01, q0);
      q1 = fmaf(vj * y0, r01, q1);
      q2 = fmaf(vj * y3, r23, q2);
      q3 = fmaf(vj * y2, r23, q3);
    }
#pragma unroll
    for (int off = 32; off; off >>= 1) {
      q0 += __shfl_xor(q0, off);
      q1 += __shfl_xor(q1, off);
      q2 += __shfl_xor(q2, off);
      q3 += __shfl_xor(q3, off);
    }
    if (lane == 0) {
      const int s = s0 + i;
      scoreLds[0][s] = vsum - 2.0f * q0;
      scoreLds[1][s] = vsum - 2.0f * q1;
      scoreLds[2][s] = vsum - 2.0f * q2;
      scoreLds[3][s] = vsum - 2.0f * q3;
    }
  }
  __syncthreads();

  // ---- softmax over s: waves 0..3 handle t = wv, lane = s ----
  if (wv < 4) {
    float sc = scoreLds[wv][lane];
    float m = sc;
#pragma unroll
    for (int off = 32; off; off >>= 1) m = fmaxf(m, __shfl_xor(m, off));
    float e = fast_exp2((sc - m) * 1.4426950408889634f);
    float ssum = e;
#pragma unroll
    for (int off = 32; off; off >>= 1) ssum += __shfl_xor(ssum, off);
    attnLds[wv][lane] = e * fast_rcp(ssum);
  }
  __syncthreads();

  // ---- context: thread h = tid covers one of 512 hidden dims ----
  {
    float c0 = 0.f, c1 = 0.f, c2 = 0.f, c3 = 0.f;
    const float* sb = srcp + (size_t)b * HID + tid;
#pragma unroll 16
    for (int s = 0; s < SRCN; ++s) {
      float sv = sb[(size_t)s * BATCH * HID];
      c0 = fmaf(attnLds[0][s], sv, c0);
      c1 = fmaf(attnLds[1][s], sv, c1);
      c2 = fmaf(attnLds[2][s], sv, c2);
      c3 = fmaf(attnLds[3][s], sv, c3);
    }
    out[((size_t)(t0 + 0) * BATCH + b) * HID + tid] = c0;
    out[((size_t)(t0 + 1) * BATCH + b) * HID + tid] = c1;
    out[((size_t)(t0 + 2) * BATCH + b) * HID + tid] = c2;
    out[((size_t)(t0 + 3) * BATCH + b) * HID + tid] = c3;
  }
}

extern "C" void kernel_launch(void* const* d_in, const int* in_sizes, int n_in,
                              void* d_out, int out_size, void* d_ws, size_t ws_size,
                              hipStream_t stream) {
  const float* h_t = (const float*)d_in[0];   // (64,32,512)
  const float* src = (const float*)d_in[1];   // (64,32,512)
  const float* Wa  = (const float*)d_in[2];   // (1024,512)
  const float* Va  = (const float*)d_in[3];   // (512,)
  float* out = (float*)d_out;                 // (64,32,512)
  float* C   = (float*)d_ws;                  // 8 MB: h_part + s_part fp32 [z][2048][512]

  proj_gemm<<<dim3(32, 8, 2), 256, 0, stream>>>(h_t, src, Wa, C);
  attn_fused<<<512, 512, 0, stream>>>(C, src, Va, out);
}